// Round 1
// baseline (524.534 us; speedup 1.0000x reference)
//
#include <hip/hip_runtime.h>
#include <math.h>

#define N_NODES 50000
#define F_IN 128
#define HD 256      // HEADS*D_HEAD
#define HID 256
#define OUT_DIM 2
#define NE 800000
#define CAP 64
#define NEG_SLOPE 0.2f

// ---------------------------------------------------------------------------
// Detect whether edge_index arrived as int64 (JAX x64 on) or int32 (default).
// int64 little-endian: every odd 32-bit word (high half) of the src segment is
// zero since values are in [0, 50000). Probability of 1024 random int32 src
// values all being zero is ~0.
__global__ __launch_bounds__(256) void detect_kernel(const int* __restrict__ w, int* flag) {
    if (threadIdx.x == 0) *flag = 1;   // assume int64
    __syncthreads();
    for (int i = threadIdx.x; i < 1024; i += 256) {
        if (w[2 * i + 1] != 0) atomicAnd(flag, 0);  // it's int32
    }
}

// cnt[n] = 1 (self loop), bucket[n*CAP+0] = n
__global__ __launch_bounds__(256) void init_cnt_kernel(int* cnt, int* bucket) {
    int n = blockIdx.x * 256 + threadIdx.x;
    if (n < N_NODES) { cnt[n] = 1; bucket[n * CAP] = n; }
}

__global__ __launch_bounds__(256) void fill_kernel(const int* __restrict__ ew,
                                                   const int* __restrict__ flag,
                                                   int* cnt, int* bucket) {
    int e = blockIdx.x * 256 + threadIdx.x;
    if (e >= NE) return;
    int is64 = *flag;
    int src, dst;
    if (is64) { src = ew[2 * e]; dst = ew[2 * NE + 2 * e]; }
    else      { src = ew[e];     dst = ew[NE + e]; }
    int pos = atomicAdd(&cnt[dst], 1);
    if (pos < CAP) bucket[dst * CAP + pos] = src;
}

// ---------------------------------------------------------------------------
// fp32 GEMM: C[N x M] = act(A[N x K] @ W[K x M] + bias)
// 64x64 tile, 256 threads (16x16), 4x4 per thread, K chunks of 32.
template <int K, int M, bool RELU, bool BIAS>
__global__ __launch_bounds__(256) void gemm_kernel(const float* __restrict__ A,
                                                   const float* __restrict__ W,
                                                   const float* __restrict__ bias,
                                                   float* __restrict__ C) {
    __shared__ float As[32][68];  // [k][row], LD=68 keeps 16B alignment, breaks bank stride
    __shared__ float Ws[32][68];  // [k][col]
    const int tid = threadIdx.x;
    const int tx = tid & 15, ty = tid >> 4;
    const int row0 = blockIdx.x * 64;
    const int col0 = blockIdx.y * 64;

    float4 acc[4];
    acc[0] = float4{0, 0, 0, 0}; acc[1] = float4{0, 0, 0, 0};
    acc[2] = float4{0, 0, 0, 0}; acc[3] = float4{0, 0, 0, 0};

    for (int k0 = 0; k0 < K; k0 += 32) {
#pragma unroll
        for (int it = 0; it < 2; ++it) {
            int q = tid + it * 256;
            // A: 64 rows x 32 k  (store transposed into As[k][row])
            int r = q >> 3, kk = (q & 7) * 4;
            float4 av = {0, 0, 0, 0};
            if (row0 + r < N_NODES)
                av = *(const float4*)&A[(size_t)(row0 + r) * K + k0 + kk];
            As[kk + 0][r] = av.x; As[kk + 1][r] = av.y;
            As[kk + 2][r] = av.z; As[kk + 3][r] = av.w;
            // W: 32 k x 64 cols
            int kw = q >> 4, cc = (q & 15) * 4;
            float4 wv = *(const float4*)&W[(size_t)(k0 + kw) * M + col0 + cc];
            *(float4*)&Ws[kw][cc] = wv;
        }
        __syncthreads();
#pragma unroll
        for (int k = 0; k < 32; ++k) {
            float4 a = *(const float4*)&As[k][ty * 4];
            float4 w = *(const float4*)&Ws[k][tx * 4];
            acc[0].x += a.x * w.x; acc[0].y += a.x * w.y; acc[0].z += a.x * w.z; acc[0].w += a.x * w.w;
            acc[1].x += a.y * w.x; acc[1].y += a.y * w.y; acc[1].z += a.y * w.z; acc[1].w += a.y * w.w;
            acc[2].x += a.z * w.x; acc[2].y += a.z * w.y; acc[2].z += a.z * w.z; acc[2].w += a.z * w.w;
            acc[3].x += a.w * w.x; acc[3].y += a.w * w.y; acc[3].z += a.w * w.z; acc[3].w += a.w * w.w;
        }
        __syncthreads();
    }

    float4 bv = {0, 0, 0, 0};
    if constexpr (BIAS) bv = *(const float4*)&bias[col0 + tx * 4];
#pragma unroll
    for (int i = 0; i < 4; ++i) {
        int row = row0 + ty * 4 + i;
        if (row < N_NODES) {
            float4 v = acc[i];
            if constexpr (BIAS) { v.x += bv.x; v.y += bv.y; v.z += bv.z; v.w += bv.w; }
            if constexpr (RELU) {
                v.x = fmaxf(v.x, 0.f); v.y = fmaxf(v.y, 0.f);
                v.z = fmaxf(v.z, 0.f); v.w = fmaxf(v.w, 0.f);
            }
            *(float4*)&C[(size_t)row * M + col0 + tx * 4] = v;
        }
    }
}

// ---------------------------------------------------------------------------
// a_s[n][h] = sum_d h[n,h,d]*att_src[h,d];  a_d likewise. One wave per node.
__global__ __launch_bounds__(256) void attn_coef_kernel(const float* __restrict__ h,
                                                        const float* __restrict__ att_src,
                                                        const float* __restrict__ att_dst,
                                                        float* __restrict__ a_s,
                                                        float* __restrict__ a_d) {
    int lane = threadIdx.x & 63;
    int wv = threadIdx.x >> 6;
    int n = blockIdx.x * 4 + wv;
    if (n >= N_NODES) return;
    float4 hv = *(const float4*)&h[(size_t)n * HD + lane * 4];
    float4 s4 = *(const float4*)&att_src[lane * 4];
    float4 d4 = *(const float4*)&att_dst[lane * 4];
    float ps = hv.x * s4.x + hv.y * s4.y + hv.z * s4.z + hv.w * s4.w;
    float pd = hv.x * d4.x + hv.y * d4.y + hv.z * d4.z + hv.w * d4.w;
#pragma unroll
    for (int off = 1; off < 16; off <<= 1) {
        ps += __shfl_xor(ps, off);
        pd += __shfl_xor(pd, off);
    }
    if ((lane & 15) == 0) {
        a_s[n * 4 + (lane >> 4)] = ps;
        a_d[n * 4 + (lane >> 4)] = pd;
    }
}

__device__ __forceinline__ float lrelu(float v) { return v >= 0.f ? v : NEG_SLOPE * v; }

// ---------------------------------------------------------------------------
// Fused per-destination softmax + weighted gather-aggregate. One wave per node.
__global__ __launch_bounds__(256) void gat_aggregate_kernel(const float* __restrict__ h,
                                                            const float* __restrict__ a_s,
                                                            const float* __restrict__ a_d,
                                                            const int* __restrict__ cnt,
                                                            const int* __restrict__ bucket,
                                                            const float* __restrict__ b_gat,
                                                            float* __restrict__ gat) {
    __shared__ int s_src[4][64];
    __shared__ float s_alpha[4][64][4];
    int lane = threadIdx.x & 63;
    int wv = threadIdx.x >> 6;
    int n = blockIdx.x * 4 + wv;   // grid is exactly 12500*4 = 50000

    int deg = cnt[n];
    if (deg > CAP) deg = CAP;
    int src = -1;
    float4 e = {-1e30f, -1e30f, -1e30f, -1e30f};
    float4 ad = *(const float4*)&a_d[n * 4];
    if (lane < deg) {
        src = bucket[n * CAP + lane];
        float4 as4 = *(const float4*)&a_s[src * 4];
        e.x = lrelu(as4.x + ad.x);
        e.y = lrelu(as4.y + ad.y);
        e.z = lrelu(as4.z + ad.z);
        e.w = lrelu(as4.w + ad.w);
    }
    // per-head max over the wave
    float4 m = e;
#pragma unroll
    for (int off = 1; off < 64; off <<= 1) {
        m.x = fmaxf(m.x, __shfl_xor(m.x, off));
        m.y = fmaxf(m.y, __shfl_xor(m.y, off));
        m.z = fmaxf(m.z, __shfl_xor(m.z, off));
        m.w = fmaxf(m.w, __shfl_xor(m.w, off));
    }
    float4 wgt = {0, 0, 0, 0};
    if (lane < deg) {
        wgt.x = __expf(e.x - m.x); wgt.y = __expf(e.y - m.y);
        wgt.z = __expf(e.z - m.z); wgt.w = __expf(e.w - m.w);
    }
    float4 s = wgt;
#pragma unroll
    for (int off = 1; off < 64; off <<= 1) {
        s.x += __shfl_xor(s.x, off); s.y += __shfl_xor(s.y, off);
        s.z += __shfl_xor(s.z, off); s.w += __shfl_xor(s.w, off);
    }
    float4 alpha;
    alpha.x = wgt.x / s.x; alpha.y = wgt.y / s.y;
    alpha.z = wgt.z / s.z; alpha.w = wgt.w / s.w;

    s_src[wv][lane] = src;
    *(float4*)&s_alpha[wv][lane][0] = alpha;
    __syncthreads();

    int head = lane >> 4;
    float4 acc = {0, 0, 0, 0};
    for (int j = 0; j < deg; ++j) {
        int sj = s_src[wv][j];
        float aj = s_alpha[wv][j][head];
        float4 hv = *(const float4*)&h[(size_t)sj * HD + lane * 4];
        acc.x += aj * hv.x; acc.y += aj * hv.y;
        acc.z += aj * hv.z; acc.w += aj * hv.w;
    }
    float4 bg = *(const float4*)&b_gat[lane * 4];
    acc.x += bg.x; acc.y += bg.y; acc.z += bg.z; acc.w += bg.w;
    *(float4*)&gat[(size_t)n * HD + lane * 4] = acc;
}

// ---------------------------------------------------------------------------
// out[n][0..1] = h2[n] @ W3 + b3. One wave per node.
__global__ __launch_bounds__(256) void out_kernel(const float* __restrict__ h2,
                                                  const float* __restrict__ W3,
                                                  const float* __restrict__ b3,
                                                  float* __restrict__ out) {
    int lane = threadIdx.x & 63;
    int wv = threadIdx.x >> 6;
    int n = blockIdx.x * 4 + wv;
    if (n >= N_NODES) return;
    float4 hv = *(const float4*)&h2[(size_t)n * HID + lane * 4];
    // W3 row-major [256][2]: 8 consecutive floats = rows k=lane*4..lane*4+3
    float4 wa = *(const float4*)&W3[lane * 8];
    float4 wb = *(const float4*)&W3[lane * 8 + 4];
    float o0 = hv.x * wa.x + hv.y * wa.z + hv.z * wb.x + hv.w * wb.z;
    float o1 = hv.x * wa.y + hv.y * wa.w + hv.z * wb.y + hv.w * wb.w;
#pragma unroll
    for (int off = 1; off < 64; off <<= 1) {
        o0 += __shfl_xor(o0, off);
        o1 += __shfl_xor(o1, off);
    }
    if (lane == 0) {
        out[n * 2 + 0] = o0 + b3[0];
        out[n * 2 + 1] = o1 + b3[1];
    }
}

// ---------------------------------------------------------------------------
extern "C" void kernel_launch(void* const* d_in, const int* in_sizes, int n_in,
                              void* d_out, int out_size, void* d_ws, size_t ws_size,
                              hipStream_t stream) {
    const float* x       = (const float*)d_in[0];
    const int*   ei      = (const int*)d_in[1];
    const float* W_gat   = (const float*)d_in[2];
    const float* att_src = (const float*)d_in[3];
    const float* att_dst = (const float*)d_in[4];
    const float* b_gat   = (const float*)d_in[5];
    const float* W1      = (const float*)d_in[6];
    const float* b1      = (const float*)d_in[7];
    const float* W2      = (const float*)d_in[8];
    const float* b2      = (const float*)d_in[9];
    const float* W3      = (const float*)d_in[10];
    const float* b3      = (const float*)d_in[11];
    float* out = (float*)d_out;

    float* ws  = (float*)d_ws;
    float* h   = ws;                              // N*256
    float* gat = h + (size_t)N_NODES * HD;        // N*256
    float* h1  = gat + (size_t)N_NODES * HD;      // N*256
    float* a_s = h1 + (size_t)N_NODES * HD;       // N*4
    float* a_d = a_s + N_NODES * 4;               // N*4
    int* cnt    = (int*)(a_d + N_NODES * 4);      // N
    int* bucket = cnt + N_NODES;                  // N*CAP
    int* flag   = bucket + (size_t)N_NODES * CAP; // 1
    float* h2 = h;  // h is dead after gat_aggregate; reuse for h2

    detect_kernel<<<1, 256, 0, stream>>>(ei, flag);
    init_cnt_kernel<<<(N_NODES + 255) / 256, 256, 0, stream>>>(cnt, bucket);
    fill_kernel<<<(NE + 255) / 256, 256, 0, stream>>>(ei, flag, cnt, bucket);

    gemm_kernel<F_IN, HD, false, false>
        <<<dim3((N_NODES + 63) / 64, HD / 64), 256, 0, stream>>>(x, W_gat, nullptr, h);
    attn_coef_kernel<<<(N_NODES + 3) / 4, 256, 0, stream>>>(h, att_src, att_dst, a_s, a_d);
    gat_aggregate_kernel<<<N_NODES / 4, 256, 0, stream>>>(h, a_s, a_d, cnt, bucket, b_gat, gat);

    gemm_kernel<HD, HID, true, true>
        <<<dim3((N_NODES + 63) / 64, HID / 64), 256, 0, stream>>>(gat, W1, b1, h1);
    gemm_kernel<HID, HID, true, true>
        <<<dim3((N_NODES + 63) / 64, HID / 64), 256, 0, stream>>>(h1, W2, b2, h2);
    out_kernel<<<(N_NODES + 3) / 4, 256, 0, stream>>>(h2, W3, b3, out);
}

// Round 2
// 315.727 us; speedup vs baseline: 1.6614x; 1.6614x over previous
//
#include <hip/hip_runtime.h>
#include <math.h>

#define N_NODES 50000
#define NP 50048          // padded to multiple of 128 for GEMM tiles
#define F_IN 128
#define HD 256            // HEADS*D_HEAD
#define HID 256
#define NE 800000
#define CAP 64
#define NEG_SLOPE 0.2f

typedef __attribute__((ext_vector_type(8))) __bf16 bf16x8;
typedef __attribute__((ext_vector_type(4))) __bf16 bf16x4;
typedef __attribute__((ext_vector_type(4))) float f32x4;

#define GLD_LDS16(g, l)                                                      \
    __builtin_amdgcn_global_load_lds(                                        \
        (const __attribute__((address_space(1))) unsigned int*)(g),          \
        (__attribute__((address_space(3))) unsigned int*)(l), 16, 0, 0)

// ---------------------------------------------------------------------------
// Detect int64 vs int32 edge_index (JAX x64 flag dependent).
__global__ __launch_bounds__(256) void detect_kernel(const int* __restrict__ w, int* flag) {
    if (threadIdx.x == 0) *flag = 1;   // assume int64
    __syncthreads();
    for (int i = threadIdx.x; i < 1024; i += 256) {
        if (w[2 * i + 1] != 0) atomicAnd(flag, 0);  // it's int32
    }
}

__global__ __launch_bounds__(256) void init_cnt_kernel(int* cnt, int* bucket) {
    int n = blockIdx.x * 256 + threadIdx.x;
    if (n < N_NODES) { cnt[n] = 1; bucket[n * CAP] = n; }
}

__global__ __launch_bounds__(256) void fill_kernel(const int* __restrict__ ew,
                                                   const int* __restrict__ flag,
                                                   int* cnt, int* bucket) {
    int e = blockIdx.x * 256 + threadIdx.x;
    if (e >= NE) return;
    int is64 = *flag;
    int src, dst;
    if (is64) { src = ew[2 * e]; dst = ew[2 * NE + 2 * e]; }
    else      { src = ew[e];     dst = ew[NE + e]; }
    int pos = atomicAdd(&cnt[dst], 1);
    if (pos < CAP) bucket[dst * CAP + pos] = src;
}

// ---------------------------------------------------------------------------
// fp32 -> bf16 convert (x). Only real rows; pad rows stay poison (never used).
__global__ __launch_bounds__(256) void convert_x_kernel(const float* __restrict__ x,
                                                        __bf16* __restrict__ xb) {
    int i = blockIdx.x * 256 + threadIdx.x;   // over N*F_IN/4
    if (i >= N_NODES * F_IN / 4) return;
    float4 v = ((const float4*)x)[i];
    bf16x4 o = {(__bf16)v.x, (__bf16)v.y, (__bf16)v.z, (__bf16)v.w};
    ((bf16x4*)xb)[i] = o;
}

// Wt[m][k] = (bf16) W[k][m]   (transpose so B-fragments are k-contiguous)
template <int K, int M>
__global__ __launch_bounds__(256) void transpose_w_kernel(const float* __restrict__ W,
                                                          __bf16* __restrict__ Wt) {
    int i = blockIdx.x * 256 + threadIdx.x;
    if (i >= M * K) return;
    int m = i / K, k = i % K;
    Wt[i] = (__bf16)W[(size_t)k * M + m];
}

// ---------------------------------------------------------------------------
// bf16 MFMA GEMM: C[NP x 256] = act(A[NP x K] @ Bt[256 x K]^T + bias)
// 128x128 tile, 4 waves (2x2 of 64x64), 16x16x32 mfma, BK=32,
// global_load_lds width-16 staging.
template <int K, bool RELU, bool BIAS>
__global__ __launch_bounds__(256) void mfma_gemm_kernel(const __bf16* __restrict__ A,
                                                        const __bf16* __restrict__ Bt,
                                                        const float* __restrict__ bias,
                                                        __bf16* __restrict__ C) {
    __shared__ __bf16 As[128 * 32];   // [row][k] row-major
    __shared__ __bf16 Bs[128 * 32];   // [col][k] row-major
    const int t = threadIdx.x;
    const int lane = t & 63;
    const int wv = t >> 6;
    const int row_off = (wv & 1) * 64;
    const int col_off = (wv >> 1) * 64;
    const int lr = lane & 15;          // m for A frag / n for B frag
    const int lk = (lane >> 4) * 8;    // k offset within BK=32
    const int row0 = blockIdx.x * 128;
    const int col0 = blockIdx.y * 128;

    f32x4 acc[4][4];
#pragma unroll
    for (int r = 0; r < 4; ++r)
#pragma unroll
        for (int c = 0; c < 4; ++c)
            acc[r][c] = f32x4{0.f, 0.f, 0.f, 0.f};

    const int sr = t >> 2;             // staging row (0..63 per shot)
    const int sk = (t & 3) * 8;        // staging k offset (8 bf16 = 16B)

    for (int k0 = 0; k0 < K; k0 += 32) {
#pragma unroll
        for (int s = 0; s < 2; ++s) {
            int r = s * 64 + sr;
            GLD_LDS16(&A[(size_t)(row0 + r) * K + k0 + sk], &As[r * 32 + sk]);
            GLD_LDS16(&Bt[(size_t)(col0 + r) * K + k0 + sk], &Bs[r * 32 + sk]);
        }
        __syncthreads();   // compiler drains vmcnt before barrier

        bf16x8 af[4], bfr[4];
#pragma unroll
        for (int i = 0; i < 4; ++i) {
            af[i]  = *(const bf16x8*)&As[(row_off + i * 16 + lr) * 32 + lk];
            bfr[i] = *(const bf16x8*)&Bs[(col_off + i * 16 + lr) * 32 + lk];
        }
#pragma unroll
        for (int r = 0; r < 4; ++r)
#pragma unroll
            for (int c = 0; c < 4; ++c)
                acc[r][c] = __builtin_amdgcn_mfma_f32_16x16x32_bf16(af[r], bfr[c], acc[r][c], 0, 0, 0);
        __syncthreads();
    }

    // epilogue: C/D map col=lane&15, row=(lane>>4)*4+i  [m89/m91]
#pragma unroll
    for (int c = 0; c < 4; ++c) {
        int col = col0 + col_off + c * 16 + lr;
        float bv = 0.f;
        if constexpr (BIAS) bv = bias[col];
#pragma unroll
        for (int r = 0; r < 4; ++r) {
#pragma unroll
            for (int i = 0; i < 4; ++i) {
                int row = row0 + row_off + r * 16 + (lane >> 4) * 4 + i;
                if (row < N_NODES) {
                    float v = acc[r][c][i] + bv;
                    if constexpr (RELU) v = fmaxf(v, 0.f);
                    C[(size_t)row * 256 + col] = (__bf16)v;
                }
            }
        }
    }
}

// ---------------------------------------------------------------------------
// a_s[n][h] = sum_d h[n,h,d]*att_src[h,d];  a_d likewise. One wave per node.
__global__ __launch_bounds__(256) void attn_coef_kernel(const __bf16* __restrict__ h,
                                                        const float* __restrict__ att_src,
                                                        const float* __restrict__ att_dst,
                                                        float* __restrict__ a_s,
                                                        float* __restrict__ a_d) {
    int lane = threadIdx.x & 63;
    int wv = threadIdx.x >> 6;
    int n = blockIdx.x * 4 + wv;
    if (n >= N_NODES) return;
    bf16x4 hv = *(const bf16x4*)&h[(size_t)n * HD + lane * 4];
    float4 s4 = *(const float4*)&att_src[lane * 4];
    float4 d4 = *(const float4*)&att_dst[lane * 4];
    float hx = (float)hv.x, hy = (float)hv.y, hz = (float)hv.z, hw = (float)hv.w;
    float ps = hx * s4.x + hy * s4.y + hz * s4.z + hw * s4.w;
    float pd = hx * d4.x + hy * d4.y + hz * d4.z + hw * d4.w;
#pragma unroll
    for (int off = 1; off < 16; off <<= 1) {
        ps += __shfl_xor(ps, off);
        pd += __shfl_xor(pd, off);
    }
    if ((lane & 15) == 0) {
        a_s[n * 4 + (lane >> 4)] = ps;
        a_d[n * 4 + (lane >> 4)] = pd;
    }
}

__device__ __forceinline__ float lrelu(float v) { return v >= 0.f ? v : NEG_SLOPE * v; }

// ---------------------------------------------------------------------------
// Fused per-destination softmax + weighted gather-aggregate. One wave/node.
// h gathered in bf16 (halves the dominant traffic), fp32 accumulate,
// bf16 output (feeds the next MFMA GEMM directly).
__global__ __launch_bounds__(256) void gat_aggregate_kernel(const __bf16* __restrict__ h,
                                                            const float* __restrict__ a_s,
                                                            const float* __restrict__ a_d,
                                                            const int* __restrict__ cnt,
                                                            const int* __restrict__ bucket,
                                                            const float* __restrict__ b_gat,
                                                            __bf16* __restrict__ gat) {
    __shared__ int s_src[4][64];
    __shared__ float s_alpha[4][64][4];
    int lane = threadIdx.x & 63;
    int wv = threadIdx.x >> 6;
    int n = blockIdx.x * 4 + wv;   // grid is exactly 12500*4 = 50000

    int deg = cnt[n];
    if (deg > CAP) deg = CAP;
    int src = -1;
    float4 e = {-1e30f, -1e30f, -1e30f, -1e30f};
    float4 ad = *(const float4*)&a_d[n * 4];
    if (lane < deg) {
        src = bucket[n * CAP + lane];
        float4 as4 = *(const float4*)&a_s[src * 4];
        e.x = lrelu(as4.x + ad.x);
        e.y = lrelu(as4.y + ad.y);
        e.z = lrelu(as4.z + ad.z);
        e.w = lrelu(as4.w + ad.w);
    }
    float4 m = e;
#pragma unroll
    for (int off = 1; off < 64; off <<= 1) {
        m.x = fmaxf(m.x, __shfl_xor(m.x, off));
        m.y = fmaxf(m.y, __shfl_xor(m.y, off));
        m.z = fmaxf(m.z, __shfl_xor(m.z, off));
        m.w = fmaxf(m.w, __shfl_xor(m.w, off));
    }
    float4 wgt = {0, 0, 0, 0};
    if (lane < deg) {
        wgt.x = __expf(e.x - m.x); wgt.y = __expf(e.y - m.y);
        wgt.z = __expf(e.z - m.z); wgt.w = __expf(e.w - m.w);
    }
    float4 s = wgt;
#pragma unroll
    for (int off = 1; off < 64; off <<= 1) {
        s.x += __shfl_xor(s.x, off); s.y += __shfl_xor(s.y, off);
        s.z += __shfl_xor(s.z, off); s.w += __shfl_xor(s.w, off);
    }
    float4 alpha;
    alpha.x = wgt.x / s.x; alpha.y = wgt.y / s.y;
    alpha.z = wgt.z / s.z; alpha.w = wgt.w / s.w;

    s_src[wv][lane] = src;
    *(float4*)&s_alpha[wv][lane][0] = alpha;
    __syncthreads();

    int head = lane >> 4;
    float ax = 0.f, ay = 0.f, az = 0.f, aw = 0.f;
    for (int j = 0; j < deg; ++j) {
        int sj = s_src[wv][j];
        float aj = s_alpha[wv][j][head];
        bf16x4 hv = *(const bf16x4*)&h[(size_t)sj * HD + lane * 4];
        ax += aj * (float)hv.x; ay += aj * (float)hv.y;
        az += aj * (float)hv.z; aw += aj * (float)hv.w;
    }
    float4 bg = *(const float4*)&b_gat[lane * 4];
    bf16x4 o = {(__bf16)(ax + bg.x), (__bf16)(ay + bg.y),
                (__bf16)(az + bg.z), (__bf16)(aw + bg.w)};
    *(bf16x4*)&gat[(size_t)n * HD + lane * 4] = o;
}

// ---------------------------------------------------------------------------
// out[n][0..1] = h2[n] @ W3 + b3. One wave per node.
__global__ __launch_bounds__(256) void out_kernel(const __bf16* __restrict__ h2,
                                                  const float* __restrict__ W3,
                                                  const float* __restrict__ b3,
                                                  float* __restrict__ out) {
    int lane = threadIdx.x & 63;
    int wv = threadIdx.x >> 6;
    int n = blockIdx.x * 4 + wv;
    if (n >= N_NODES) return;
    bf16x4 hv = *(const bf16x4*)&h2[(size_t)n * HID + lane * 4];
    float hx = (float)hv.x, hy = (float)hv.y, hz = (float)hv.z, hw = (float)hv.w;
    float4 wa = *(const float4*)&W3[lane * 8];
    float4 wb = *(const float4*)&W3[lane * 8 + 4];
    float o0 = hx * wa.x + hy * wa.z + hz * wb.x + hw * wb.z;
    float o1 = hx * wa.y + hy * wa.w + hz * wb.y + hw * wb.w;
#pragma unroll
    for (int off = 1; off < 64; off <<= 1) {
        o0 += __shfl_xor(o0, off);
        o1 += __shfl_xor(o1, off);
    }
    if (lane == 0) {
        out[n * 2 + 0] = o0 + b3[0];
        out[n * 2 + 1] = o1 + b3[1];
    }
}

// ---------------------------------------------------------------------------
extern "C" void kernel_launch(void* const* d_in, const int* in_sizes, int n_in,
                              void* d_out, int out_size, void* d_ws, size_t ws_size,
                              hipStream_t stream) {
    const float* x       = (const float*)d_in[0];
    const int*   ei      = (const int*)d_in[1];
    const float* W_gat   = (const float*)d_in[2];
    const float* att_src = (const float*)d_in[3];
    const float* att_dst = (const float*)d_in[4];
    const float* b_gat   = (const float*)d_in[5];
    const float* W1      = (const float*)d_in[6];
    const float* b1      = (const float*)d_in[7];
    const float* W2      = (const float*)d_in[8];
    const float* b2      = (const float*)d_in[9];
    const float* W3      = (const float*)d_in[10];
    const float* b3      = (const float*)d_in[11];
    float* out = (float*)d_out;

    char* ws = (char*)d_ws;
    __bf16* x_bf  = (__bf16*)ws;                       ws += (size_t)NP * F_IN * 2;  // 12.8 MB
    __bf16* h_bf  = (__bf16*)ws;                       ws += (size_t)NP * HD * 2;    // 25.6 MB
    __bf16* gat_bf = (__bf16*)ws;                      ws += (size_t)NP * HD * 2;
    __bf16* h1_bf = (__bf16*)ws;                       ws += (size_t)NP * HID * 2;
    __bf16* h2_bf = (__bf16*)ws;                       ws += (size_t)NP * HID * 2;
    __bf16* Wg_t  = (__bf16*)ws;                       ws += (size_t)HD * F_IN * 2;
    __bf16* W1_t  = (__bf16*)ws;                       ws += (size_t)HID * HD * 2;
    __bf16* W2_t  = (__bf16*)ws;                       ws += (size_t)HID * HID * 2;
    float* a_s    = (float*)ws;                        ws += (size_t)N_NODES * 4 * 4;
    float* a_d    = (float*)ws;                        ws += (size_t)N_NODES * 4 * 4;
    int* cnt      = (int*)ws;                          ws += (size_t)N_NODES * 4;
    int* bucket   = (int*)ws;                          ws += (size_t)N_NODES * CAP * 4;
    int* flag     = (int*)ws;

    detect_kernel<<<1, 256, 0, stream>>>(ei, flag);
    init_cnt_kernel<<<(N_NODES + 255) / 256, 256, 0, stream>>>(cnt, bucket);
    fill_kernel<<<(NE + 255) / 256, 256, 0, stream>>>(ei, flag, cnt, bucket);

    convert_x_kernel<<<(N_NODES * F_IN / 4 + 255) / 256, 256, 0, stream>>>(x, x_bf);
    transpose_w_kernel<F_IN, HD><<<(HD * F_IN + 255) / 256, 256, 0, stream>>>(W_gat, Wg_t);
    transpose_w_kernel<HD, HID><<<(HID * HD + 255) / 256, 256, 0, stream>>>(W1, W1_t);
    transpose_w_kernel<HID, HID><<<(HID * HID + 255) / 256, 256, 0, stream>>>(W2, W2_t);

    mfma_gemm_kernel<F_IN, false, false>
        <<<dim3(NP / 128, 2), 256, 0, stream>>>(x_bf, Wg_t, nullptr, h_bf);
    attn_coef_kernel<<<(N_NODES + 3) / 4, 256, 0, stream>>>(h_bf, att_src, att_dst, a_s, a_d);
    gat_aggregate_kernel<<<N_NODES / 4, 256, 0, stream>>>(h_bf, a_s, a_d, cnt, bucket, b_gat, gat_bf);

    mfma_gemm_kernel<HD, true, true>
        <<<dim3(NP / 128, 2), 256, 0, stream>>>(gat_bf, W1_t, b1, h1_bf);
    mfma_gemm_kernel<HID, true, true>
        <<<dim3(NP / 128, 2), 256, 0, stream>>>(h1_bf, W2_t, b2, h2_bf);
    out_kernel<<<(N_NODES + 3) / 4, 256, 0, stream>>>(h2_bf, W3, b3, out);
}

// Round 3
// 257.827 us; speedup vs baseline: 2.0344x; 1.2246x over previous
//
#include <hip/hip_runtime.h>
#include <math.h>

#define N_NODES 50000
#define NP 50048          // padded to multiple of 64 for GEMM tiles
#define F_IN 128
#define HD 256            // HEADS*D_HEAD
#define HID 256
#define NE 800000
#define CAP 64
#define NEG_SLOPE 0.2f

typedef __attribute__((ext_vector_type(8))) __bf16 bf16x8;
typedef __attribute__((ext_vector_type(4))) __bf16 bf16x4;
typedef __attribute__((ext_vector_type(4))) float f32x4;

#define GLD_LDS16(g, l)                                                      \
    __builtin_amdgcn_global_load_lds(                                        \
        (const __attribute__((address_space(1))) unsigned int*)(g),          \
        (__attribute__((address_space(3))) unsigned int*)(l), 16, 0, 0)

// ---------------------------------------------------------------------------
// prep: x->bf16 convert, cnt/bucket init, 3 weight transposes. One launch.
#define PB_CONV 6250
#define PB_INIT 196
#define PB_WG   128
#define PB_W1   256
#define PB_W2   256

__global__ __launch_bounds__(256) void prep_kernel(const float* __restrict__ x,
                                                   const float* __restrict__ Wg,
                                                   const float* __restrict__ W1,
                                                   const float* __restrict__ W2,
                                                   __bf16* __restrict__ xb,
                                                   __bf16* __restrict__ Wg_t,
                                                   __bf16* __restrict__ W1_t,
                                                   __bf16* __restrict__ W2_t,
                                                   int* __restrict__ cnt,
                                                   int* __restrict__ bucket) {
    int b = blockIdx.x, t = threadIdx.x;
    if (b < PB_CONV) {                       // exactly N*F_IN/4 = 1.6M float4
        int i = b * 256 + t;
        float4 v = ((const float4*)x)[i];
        bf16x4 o = {(__bf16)v.x, (__bf16)v.y, (__bf16)v.z, (__bf16)v.w};
        ((bf16x4*)xb)[i] = o;
    } else if (b < PB_CONV + PB_INIT) {
        int n = (b - PB_CONV) * 256 + t;
        if (n < N_NODES) { cnt[n] = 1; bucket[n * CAP] = n; }
    } else if (b < PB_CONV + PB_INIT + PB_WG) {
        int i = (b - PB_CONV - PB_INIT) * 256 + t;   // 32768 = HD*F_IN
        int m = i >> 7, k = i & 127;
        Wg_t[i] = (__bf16)Wg[(size_t)k * HD + m];
    } else if (b < PB_CONV + PB_INIT + PB_WG + PB_W1) {
        int i = (b - PB_CONV - PB_INIT - PB_WG) * 256 + t;  // 65536
        int m = i >> 8, k = i & 255;
        W1_t[i] = (__bf16)W1[(size_t)k * HID + m];
    } else {
        int i = (b - PB_CONV - PB_INIT - PB_WG - PB_W1) * 256 + t;
        int m = i >> 8, k = i & 255;
        W2_t[i] = (__bf16)W2[(size_t)k * HID + m];
    }
}

// ---------------------------------------------------------------------------
// fill: int64-vs-int32 detection folded in via per-wave ballot of high words.
// For int64 data all high words are 0; for int32 they're random node indices
// (64 simultaneous zeros has probability ~(1/50000)^64).
__global__ __launch_bounds__(256) void fill_kernel(const int* __restrict__ ew,
                                                   int* cnt, int* bucket) {
    int e = blockIdx.x * 256 + threadIdx.x;   // grid is exactly NE/256
    int hi = ew[2 * e + 1];
    unsigned long long bal = __ballot(hi != 0);
    int src, dst;
    if (bal == 0) { src = ew[2 * e]; dst = ew[2 * NE + 2 * e]; }  // int64
    else          { src = ew[e];     dst = ew[NE + e]; }          // int32
    int pos = atomicAdd(&cnt[dst], 1);
    if (pos < CAP) bucket[dst * CAP + pos] = src;
}

// ---------------------------------------------------------------------------
// GEMM1 (x @ W_gat) fused with attention coefficients.
// Tile 64 rows x 256 cols, 4 waves (each 64x64, col_off = wv*64 = head*64).
__global__ __launch_bounds__(256) void gemm1_attn_kernel(const __bf16* __restrict__ A,
                                                         const __bf16* __restrict__ Bt,
                                                         const float* __restrict__ att_src,
                                                         const float* __restrict__ att_dst,
                                                         __bf16* __restrict__ h,
                                                         float* __restrict__ a_s,
                                                         float* __restrict__ a_d) {
    __shared__ __bf16 As[64 * 32];    // [row][k]
    __shared__ __bf16 Bs[256 * 32];   // [col][k]
    const int t = threadIdx.x;
    const int lane = t & 63, wv = t >> 6;
    const int lr = lane & 15, q = lane >> 4, lk = q * 8;
    const int col_off = wv * 64;
    const int row0 = blockIdx.x * 64;
    const int sr = t >> 2, sk = (t & 3) * 8;

    f32x4 acc[4][4];
#pragma unroll
    for (int r = 0; r < 4; ++r)
#pragma unroll
        for (int c = 0; c < 4; ++c) acc[r][c] = f32x4{0.f, 0.f, 0.f, 0.f};

    for (int k0 = 0; k0 < F_IN; k0 += 32) {
        GLD_LDS16(&A[(size_t)(row0 + sr) * F_IN + k0 + sk], &As[sr * 32 + sk]);
#pragma unroll
        for (int s = 0; s < 4; ++s) {
            int r = s * 64 + sr;
            GLD_LDS16(&Bt[(size_t)r * F_IN + k0 + sk], &Bs[r * 32 + sk]);
        }
        __syncthreads();
        bf16x8 af[4], bfr[4];
#pragma unroll
        for (int i = 0; i < 4; ++i) {
            af[i]  = *(const bf16x8*)&As[(i * 16 + lr) * 32 + lk];
            bfr[i] = *(const bf16x8*)&Bs[(col_off + i * 16 + lr) * 32 + lk];
        }
#pragma unroll
        for (int r = 0; r < 4; ++r)
#pragma unroll
            for (int c = 0; c < 4; ++c)
                acc[r][c] = __builtin_amdgcn_mfma_f32_16x16x32_bf16(af[r], bfr[c], acc[r][c], 0, 0, 0);
        __syncthreads();
    }

    // epilogue: write h (bf16) + fused a_s/a_d (head = wv since att flat [h*64+d])
    float asv[4], adv[4];
#pragma unroll
    for (int c = 0; c < 4; ++c) {
        int col = col_off + c * 16 + lr;
        asv[c] = att_src[col];
        adv[c] = att_dst[col];
    }
    float ps[4][4], pd[4][4];
#pragma unroll
    for (int r = 0; r < 4; ++r)
#pragma unroll
        for (int i = 0; i < 4; ++i) { ps[r][i] = 0.f; pd[r][i] = 0.f; }

#pragma unroll
    for (int c = 0; c < 4; ++c) {
        int col = col_off + c * 16 + lr;
#pragma unroll
        for (int r = 0; r < 4; ++r) {
#pragma unroll
            for (int i = 0; i < 4; ++i) {
                int row = row0 + r * 16 + q * 4 + i;   // < NP by construction
                float v = acc[r][c][i];
                h[(size_t)row * HD + col] = (__bf16)v;
                ps[r][i] += v * asv[c];
                pd[r][i] += v * adv[c];
            }
        }
    }
#pragma unroll
    for (int r = 0; r < 4; ++r)
#pragma unroll
        for (int i = 0; i < 4; ++i) {
#pragma unroll
            for (int m = 1; m < 16; m <<= 1) {
                ps[r][i] += __shfl_xor(ps[r][i], m);
                pd[r][i] += __shfl_xor(pd[r][i], m);
            }
        }
    if (lr == 0) {
#pragma unroll
        for (int r = 0; r < 4; ++r)
#pragma unroll
            for (int i = 0; i < 4; ++i) {
                int row = row0 + r * 16 + q * 4 + i;
                a_s[row * 4 + wv] = ps[r][i];
                a_d[row * 4 + wv] = pd[r][i];
            }
    }
}

__device__ __forceinline__ float lrelu(float v) { return v >= 0.f ? v : NEG_SLOPE * v; }

// ---------------------------------------------------------------------------
// Fused per-destination softmax + weighted gather-aggregate. One wave/node.
__global__ __launch_bounds__(256) void gat_aggregate_kernel(const __bf16* __restrict__ h,
                                                            const float* __restrict__ a_s,
                                                            const float* __restrict__ a_d,
                                                            const int* __restrict__ cnt,
                                                            const int* __restrict__ bucket,
                                                            const float* __restrict__ b_gat,
                                                            __bf16* __restrict__ gat) {
    __shared__ int s_src[4][64];
    __shared__ float s_alpha[4][64][4];
    int lane = threadIdx.x & 63;
    int wv = threadIdx.x >> 6;
    int n = blockIdx.x * 4 + wv;   // grid is exactly 12500*4 = 50000

    int deg = cnt[n];
    if (deg > CAP) deg = CAP;
    int src = -1;
    float4 e = {-1e30f, -1e30f, -1e30f, -1e30f};
    float4 ad = *(const float4*)&a_d[n * 4];
    if (lane < deg) {
        src = bucket[n * CAP + lane];
        float4 as4 = *(const float4*)&a_s[src * 4];
        e.x = lrelu(as4.x + ad.x);
        e.y = lrelu(as4.y + ad.y);
        e.z = lrelu(as4.z + ad.z);
        e.w = lrelu(as4.w + ad.w);
    }
    float4 m = e;
#pragma unroll
    for (int off = 1; off < 64; off <<= 1) {
        m.x = fmaxf(m.x, __shfl_xor(m.x, off));
        m.y = fmaxf(m.y, __shfl_xor(m.y, off));
        m.z = fmaxf(m.z, __shfl_xor(m.z, off));
        m.w = fmaxf(m.w, __shfl_xor(m.w, off));
    }
    float4 wgt = {0, 0, 0, 0};
    if (lane < deg) {
        wgt.x = __expf(e.x - m.x); wgt.y = __expf(e.y - m.y);
        wgt.z = __expf(e.z - m.z); wgt.w = __expf(e.w - m.w);
    }
    float4 s = wgt;
#pragma unroll
    for (int off = 1; off < 64; off <<= 1) {
        s.x += __shfl_xor(s.x, off); s.y += __shfl_xor(s.y, off);
        s.z += __shfl_xor(s.z, off); s.w += __shfl_xor(s.w, off);
    }
    float4 alpha;
    alpha.x = wgt.x / s.x; alpha.y = wgt.y / s.y;
    alpha.z = wgt.z / s.z; alpha.w = wgt.w / s.w;

    s_src[wv][lane] = src;
    *(float4*)&s_alpha[wv][lane][0] = alpha;
    __syncthreads();

    int head = lane >> 4;
    float ax = 0.f, ay = 0.f, az = 0.f, aw = 0.f;
    int j = 0;
    for (; j + 4 <= deg; j += 4) {       // 4 outstanding gathers
        int s0 = s_src[wv][j], s1 = s_src[wv][j + 1];
        int s2 = s_src[wv][j + 2], s3 = s_src[wv][j + 3];
        float a0 = s_alpha[wv][j][head],     a1 = s_alpha[wv][j + 1][head];
        float a2 = s_alpha[wv][j + 2][head], a3 = s_alpha[wv][j + 3][head];
        bf16x4 h0 = *(const bf16x4*)&h[(size_t)s0 * HD + lane * 4];
        bf16x4 h1 = *(const bf16x4*)&h[(size_t)s1 * HD + lane * 4];
        bf16x4 h2 = *(const bf16x4*)&h[(size_t)s2 * HD + lane * 4];
        bf16x4 h3 = *(const bf16x4*)&h[(size_t)s3 * HD + lane * 4];
        ax += a0 * (float)h0.x + a1 * (float)h1.x + a2 * (float)h2.x + a3 * (float)h3.x;
        ay += a0 * (float)h0.y + a1 * (float)h1.y + a2 * (float)h2.y + a3 * (float)h3.y;
        az += a0 * (float)h0.z + a1 * (float)h1.z + a2 * (float)h2.z + a3 * (float)h3.z;
        aw += a0 * (float)h0.w + a1 * (float)h1.w + a2 * (float)h2.w + a3 * (float)h3.w;
    }
    for (; j < deg; ++j) {
        int sj = s_src[wv][j];
        float aj = s_alpha[wv][j][head];
        bf16x4 hv = *(const bf16x4*)&h[(size_t)sj * HD + lane * 4];
        ax += aj * (float)hv.x; ay += aj * (float)hv.y;
        az += aj * (float)hv.z; aw += aj * (float)hv.w;
    }
    float4 bg = *(const float4*)&b_gat[lane * 4];
    bf16x4 o = {(__bf16)(ax + bg.x), (__bf16)(ay + bg.y),
                (__bf16)(az + bg.z), (__bf16)(aw + bg.w)};
    *(bf16x4*)&gat[(size_t)n * HD + lane * 4] = o;
}

// ---------------------------------------------------------------------------
// Fused MLP: out = relu(relu(gat@W1+b1)@W2+b2)@W3 + b3, one kernel.
// Tile 64 rows x 256 cols; h1 lives in LDS chunked [k-chunk][row][kk] so
// stage-2 A-frag reads use the same addressing as the staging buffers.
__global__ __launch_bounds__(256) void fused_mlp_kernel(const __bf16* __restrict__ A,
                                                        const __bf16* __restrict__ W1t,
                                                        const __bf16* __restrict__ W2t,
                                                        const float* __restrict__ b1,
                                                        const float* __restrict__ b2,
                                                        const float* __restrict__ W3,
                                                        const float* __restrict__ b3,
                                                        float* __restrict__ out) {
    __shared__ __bf16 As[64 * 32];        // 4 KB
    __shared__ __bf16 Ws[256 * 32];       // 16 KB
    __shared__ __bf16 h1s[8 * 64 * 32];   // 32 KB, chunk c holds k in [32c,32c+32)
    __shared__ float s_out[64][2];
    const int t = threadIdx.x;
    const int lane = t & 63, wv = t >> 6;
    const int lr = lane & 15, q = lane >> 4, lk = q * 8;
    const int col_off = wv * 64;
    const int row0 = blockIdx.x * 64;
    const int sr = t >> 2, sk = (t & 3) * 8;

    if (t < 128) ((float*)s_out)[t] = 0.f;

    f32x4 acc[4][4];
#pragma unroll
    for (int r = 0; r < 4; ++r)
#pragma unroll
        for (int c = 0; c < 4; ++c) acc[r][c] = f32x4{0.f, 0.f, 0.f, 0.f};

    // ---- stage 1: h1 = relu(gat @ W1 + b1) -> LDS
    for (int k0 = 0; k0 < HD; k0 += 32) {
        GLD_LDS16(&A[(size_t)(row0 + sr) * HD + k0 + sk], &As[sr * 32 + sk]);
#pragma unroll
        for (int s = 0; s < 4; ++s) {
            int r = s * 64 + sr;
            GLD_LDS16(&W1t[(size_t)r * HD + k0 + sk], &Ws[r * 32 + sk]);
        }
        __syncthreads();
        bf16x8 af[4], bfr[4];
#pragma unroll
        for (int i = 0; i < 4; ++i) {
            af[i]  = *(const bf16x8*)&As[(i * 16 + lr) * 32 + lk];
            bfr[i] = *(const bf16x8*)&Ws[(col_off + i * 16 + lr) * 32 + lk];
        }
#pragma unroll
        for (int r = 0; r < 4; ++r)
#pragma unroll
            for (int c = 0; c < 4; ++c)
                acc[r][c] = __builtin_amdgcn_mfma_f32_16x16x32_bf16(af[r], bfr[c], acc[r][c], 0, 0, 0);
        __syncthreads();
    }
#pragma unroll
    for (int c = 0; c < 4; ++c) {
        int col = col_off + c * 16 + lr;
        float bv = b1[col];
        int cb = (col >> 5) * 2048;
        int kk = col & 31;
#pragma unroll
        for (int r = 0; r < 4; ++r)
#pragma unroll
            for (int i = 0; i < 4; ++i) {
                int row = r * 16 + q * 4 + i;
                float v = fmaxf(acc[r][c][i] + bv, 0.f);
                h1s[cb + row * 32 + kk] = (__bf16)v;
                acc[r][c][i] = 0.f;
            }
    }
    __syncthreads();

    // ---- stage 2: h2 = gat' = h1 @ W2 (+b2, relu in stage 3)
    for (int k0 = 0; k0 < HID; k0 += 32) {
#pragma unroll
        for (int s = 0; s < 4; ++s) {
            int r = s * 64 + sr;
            GLD_LDS16(&W2t[(size_t)r * HID + k0 + sk], &Ws[r * 32 + sk]);
        }
        __syncthreads();
        const int cb = (k0 >> 5) * 2048;
        bf16x8 af[4], bfr[4];
#pragma unroll
        for (int i = 0; i < 4; ++i) {
            af[i]  = *(const bf16x8*)&h1s[cb + (i * 16 + lr) * 32 + lk];
            bfr[i] = *(const bf16x8*)&Ws[(col_off + i * 16 + lr) * 32 + lk];
        }
#pragma unroll
        for (int r = 0; r < 4; ++r)
#pragma unroll
            for (int c = 0; c < 4; ++c)
                acc[r][c] = __builtin_amdgcn_mfma_f32_16x16x32_bf16(af[r], bfr[c], acc[r][c], 0, 0, 0);
        __syncthreads();
    }

    // ---- stage 3: out = relu(h2+b2) @ W3 + b3 (fp32 throughout)
    float b2v[4], w30[4], w31[4];
#pragma unroll
    for (int c = 0; c < 4; ++c) {
        int col = col_off + c * 16 + lr;
        b2v[c] = b2[col];
        w30[c] = W3[col * 2];
        w31[c] = W3[col * 2 + 1];
    }
#pragma unroll
    for (int r = 0; r < 4; ++r) {
#pragma unroll
        for (int i = 0; i < 4; ++i) {
            float o0 = 0.f, o1 = 0.f;
#pragma unroll
            for (int c = 0; c < 4; ++c) {
                float v = fmaxf(acc[r][c][i] + b2v[c], 0.f);
                o0 += v * w30[c];
                o1 += v * w31[c];
            }
#pragma unroll
            for (int m = 1; m < 16; m <<= 1) {
                o0 += __shfl_xor(o0, m);
                o1 += __shfl_xor(o1, m);
            }
            if (lr == 0) {
                int row = r * 16 + q * 4 + i;
                atomicAdd(&s_out[row][0], o0);
                atomicAdd(&s_out[row][1], o1);
            }
        }
    }
    __syncthreads();
    if (t < 128) {
        int row = t >> 1, o = t & 1;
        int g = row0 + row;
        if (g < N_NODES) out[g * 2 + o] = s_out[row][o] + b3[o];
    }
}

// ---------------------------------------------------------------------------
extern "C" void kernel_launch(void* const* d_in, const int* in_sizes, int n_in,
                              void* d_out, int out_size, void* d_ws, size_t ws_size,
                              hipStream_t stream) {
    const float* x       = (const float*)d_in[0];
    const int*   ei      = (const int*)d_in[1];
    const float* W_gat   = (const float*)d_in[2];
    const float* att_src = (const float*)d_in[3];
    const float* att_dst = (const float*)d_in[4];
    const float* b_gat   = (const float*)d_in[5];
    const float* W1      = (const float*)d_in[6];
    const float* b1      = (const float*)d_in[7];
    const float* W2      = (const float*)d_in[8];
    const float* b2      = (const float*)d_in[9];
    const float* W3      = (const float*)d_in[10];
    const float* b3      = (const float*)d_in[11];
    float* out = (float*)d_out;

    char* ws = (char*)d_ws;
    __bf16* x_bf   = (__bf16*)ws;  ws += (size_t)NP * F_IN * 2;
    __bf16* h_bf   = (__bf16*)ws;  ws += (size_t)NP * HD * 2;
    __bf16* gat_bf = (__bf16*)ws;  ws += (size_t)NP * HD * 2;
    __bf16* Wg_t   = (__bf16*)ws;  ws += (size_t)HD * F_IN * 2;
    __bf16* W1_t   = (__bf16*)ws;  ws += (size_t)HID * HD * 2;
    __bf16* W2_t   = (__bf16*)ws;  ws += (size_t)HID * HID * 2;
    float* a_s     = (float*)ws;   ws += (size_t)NP * 4 * 4;
    float* a_d     = (float*)ws;   ws += (size_t)NP * 4 * 4;
    int* cnt       = (int*)ws;     ws += (size_t)N_NODES * 4;
    int* bucket    = (int*)ws;     ws += (size_t)N_NODES * CAP * 4;

    prep_kernel<<<PB_CONV + PB_INIT + PB_WG + PB_W1 + PB_W2, 256, 0, stream>>>(
        x, W_gat, W1, W2, x_bf, Wg_t, W1_t, W2_t, cnt, bucket);
    fill_kernel<<<NE / 256, 256, 0, stream>>>(ei, cnt, bucket);
    gemm1_attn_kernel<<<NP / 64, 256, 0, stream>>>(x_bf, Wg_t, att_src, att_dst,
                                                   h_bf, a_s, a_d);
    gat_aggregate_kernel<<<N_NODES / 4, 256, 0, stream>>>(h_bf, a_s, a_d, cnt, bucket,
                                                          b_gat, gat_bf);
    fused_mlp_kernel<<<NP / 64, 256, 0, stream>>>(gat_bf, W1_t, W2_t, b1, b2, W3, b3, out);
}